// Round 6
// baseline (1061.810 us; speedup 1.0000x reference)
//
#include <hip/hip_runtime.h>

#define B_ 16
#define N_ 4096
#define CIN_ 64
#define COUT_ 128
#define K_ 16
#define M_ 1024

typedef float f32x2 __attribute__((ext_vector_type(2)));
typedef unsigned long long u64;

#define DPPF(m, ctrl)                                                          \
  m = fmaxf(m, __int_as_float(__builtin_amdgcn_update_dpp(                     \
                  0, __float_as_int(m), ctrl, 0xF, 0xF, true)))
#define DPPI(e, ctrl)                                                          \
  e = max(e, __builtin_amdgcn_update_dpp(0, e, ctrl, 0xF, 0xF, true))

__device__ __forceinline__ unsigned mono32(float d) {
  unsigned u = __float_as_uint(d);
  return u ^ (unsigned)(((int)u >> 31) | 0x80000000);
}
__device__ __forceinline__ unsigned short f2bf(float x) {
  const unsigned u = __float_as_uint(x);
  return (unsigned short)((u + 0x7FFF + ((u >> 16) & 1)) >> 16);  // RNE
}

// Control block layout (in ws, zeroed by one memset):
//   [0..2048)    stats: sum[128], sumsq[128], scale[128], shift[128]
//   [2048..2112) prog[16]
//   [2112]       lin_done
//   [2116]       stats_flag
//   [2176..3200) qt_done[256]
// Single fused kernel. Roles by blockIdx.x:
//   [0,16)        FPS (1/batch; 256 compute lanes + 4 idle waves matching the
//                 one barrier/step; publishes prog[b] every 64 steps).
//   [16,528)      linear+stats; block seeing lin_done==511 computes BN
//                 scale/shift and releases stats_flag.
//   [528,..)      kNN split blocks (qt-major). Last split of (b,qt) merges the
//                 S sorted lists, gathers bf16 h, BN+maxpool, writes all
//                 outputs for its 64 queries. No post-kernels.
__global__ __launch_bounds__(512) void mega_kernel(
    const float* __restrict__ pos, const float* __restrict__ features,
    const float* __restrict__ W, const float* __restrict__ bias,
    const float* __restrict__ gamma, const float* __restrict__ beta,
    int* __restrict__ fps_idx, unsigned short* __restrict__ h,
    float* __restrict__ ctrl, u64* __restrict__ cand,
    float* __restrict__ out, int S, int batch_as_i64) {
  __shared__ __align__(16) char smem[84 * 1024];
  const int id = blockIdx.x;
  const int t = threadIdx.x;
  float* stats = ctrl;
  int* prog = (int*)(ctrl + 512);
  int* lin_done = (int*)(ctrl + 528);
  int* stats_flag = (int*)(ctrl + 529);
  int* qt_done = (int*)(ctrl + 544);
  const int A = B_ * M_ * COUT_;
  const int P = B_ * M_ * 3;

  if (id < B_) {
    // ------------------------- FPS -------------------------
    const int b = id;
    float4* Pp = (float4*)smem;       // 64 KB
    u64* red = (u64*)(smem + 65536);  // [2][4]
    const float* pb = pos + (size_t)b * N_ * 3;
    for (int i = t; i < N_; i += 512)
      Pp[i] = make_float4(pb[i * 3], pb[i * 3 + 1], pb[i * 3 + 2], 0.f);
    __syncthreads();
    if (t < 256) {
      f32x2 px[8], py[8], pz[8], md[8];
#pragma unroll
      for (int j = 0; j < 8; ++j) {
        const float4 lo = Pp[t + 512 * j];
        const float4 hi = Pp[t + 512 * j + 256];
        px[j] = (f32x2){lo.x, hi.x};
        py[j] = (f32x2){lo.y, hi.y};
        pz[j] = (f32x2){lo.z, hi.z};
        md[j] = (f32x2){1e10f, 1e10f};
      }
      if (t == 0) fps_idx[b * M_] = 0;
      const int wv = t >> 6, ln = t & 63;
      const int e0 = 65535 - t;  // enc = 65535 - idx; idx = t + 256*(2j+h)
      float4 lp = Pp[0];
      for (int step = 1; step < M_; ++step) {
        const f32x2 lx = {lp.x, lp.x}, ly = {lp.y, lp.y}, lz = {lp.z, lp.z};
        float bestd = -1.0f;
        int be = 0;
        {
#pragma clang fp contract(off)
#pragma unroll
          for (int j = 0; j < 8; ++j) {
            const f32x2 dx = px[j] - lx;
            const f32x2 dy = py[j] - ly;
            const f32x2 dz = pz[j] - lz;
            const f32x2 s1 = dx * dx;
            const f32x2 s2 = dy * dy;
            const f32x2 s3 = dz * dz;
            const f32x2 d = (s1 + s2) + s3;  // exact reference order
            f32x2 nd;
            nd.x = fminf(md[j].x, d.x);
            nd.y = fminf(md[j].y, d.y);
            md[j] = nd;
            if (nd.x > bestd) { bestd = nd.x; be = e0 - (j << 9); }
            if (nd.y > bestd) { bestd = nd.y; be = e0 - (j << 9) - 256; }
          }
        }
        float m = bestd;
        DPPF(m, 0x111); DPPF(m, 0x112); DPPF(m, 0x114); DPPF(m, 0x118);
        DPPF(m, 0x142); DPPF(m, 0x143);
        const float wm =
            __int_as_float(__builtin_amdgcn_readlane(__float_as_int(m), 63));
        int enc = (bestd == wm) ? be : 0;
        DPPI(enc, 0x111); DPPI(enc, 0x112); DPPI(enc, 0x114); DPPI(enc, 0x118);
        DPPI(enc, 0x142); DPPI(enc, 0x143);
        const int wenc = __builtin_amdgcn_readlane(enc, 63);
        if (ln == 0)
          red[(step & 1) * 4 + wv] =
              ((u64)__float_as_uint(wm) << 32) | (unsigned)wenc;
        __syncthreads();
        const u64* rb = &red[(step & 1) * 4];
        u64 rr = rb[0] > rb[1] ? rb[0] : rb[1];
        const u64 r2 = rb[2] > rb[3] ? rb[2] : rb[3];
        if (r2 > rr) rr = r2;
        const int last = 65535 - (int)(unsigned)(rr & 0xFFFFu);
        lp = Pp[last];
        if (t == 0) {
          fps_idx[b * M_ + step] = last;
          if ((step & 63) == 63)
            __hip_atomic_store(&prog[b], (step >> 6) + 1, __ATOMIC_RELEASE,
                               __HIP_MEMORY_SCOPE_AGENT);
        }
      }
    } else {
      for (int step = 1; step < M_; ++step) __syncthreads();
    }
    return;
  }

  if (id < B_ + 512) {
    // ---------------- linear (h bf16) + stats; last block finalizes BN ------
    const int lid = id - B_;
    float* ls = (float*)smem;  // 256 floats
    for (int i = t; i < 256; i += 512) ls[i] = 0.f;
    __syncthreads();
    const int o4 = (t & 31) << 2;
    const int rl = t >> 5;
    const float4 bv = *(const float4*)(bias + o4);
    float4 s4 = {0, 0, 0, 0}, ss4 = {0, 0, 0, 0};
    for (int i = 0; i < 8; ++i) {
      const int r = lid * 128 + rl * 8 + i;
      const float4* fr = (const float4*)(features + (size_t)r * CIN_);
      float4 acc = bv;
#pragma unroll
      for (int c4 = 0; c4 < 16; ++c4) {
        const float4 fv = fr[c4];
        const float* wr = W + (size_t)(c4 * 4) * COUT_ + o4;
        const float4 w0 = *(const float4*)(wr);
        const float4 w1 = *(const float4*)(wr + COUT_);
        const float4 w2 = *(const float4*)(wr + 2 * COUT_);
        const float4 w3 = *(const float4*)(wr + 3 * COUT_);
        acc.x = fmaf(fv.x, w0.x, acc.x); acc.y = fmaf(fv.x, w0.y, acc.y);
        acc.z = fmaf(fv.x, w0.z, acc.z); acc.w = fmaf(fv.x, w0.w, acc.w);
        acc.x = fmaf(fv.y, w1.x, acc.x); acc.y = fmaf(fv.y, w1.y, acc.y);
        acc.z = fmaf(fv.y, w1.z, acc.z); acc.w = fmaf(fv.y, w1.w, acc.w);
        acc.x = fmaf(fv.z, w2.x, acc.x); acc.y = fmaf(fv.z, w2.y, acc.y);
        acc.z = fmaf(fv.z, w2.z, acc.z); acc.w = fmaf(fv.z, w2.w, acc.w);
        acc.x = fmaf(fv.w, w3.x, acc.x); acc.y = fmaf(fv.w, w3.y, acc.y);
        acc.z = fmaf(fv.w, w3.z, acc.z); acc.w = fmaf(fv.w, w3.w, acc.w);
      }
      *(ushort4*)(h + (size_t)r * COUT_ + o4) =
          make_ushort4(f2bf(acc.x), f2bf(acc.y), f2bf(acc.z), f2bf(acc.w));
      s4.x += acc.x; s4.y += acc.y; s4.z += acc.z; s4.w += acc.w;
      ss4.x = fmaf(acc.x, acc.x, ss4.x); ss4.y = fmaf(acc.y, acc.y, ss4.y);
      ss4.z = fmaf(acc.z, acc.z, ss4.z); ss4.w = fmaf(acc.w, acc.w, ss4.w);
    }
    atomicAdd(&ls[o4 + 0], s4.x); atomicAdd(&ls[o4 + 1], s4.y);
    atomicAdd(&ls[o4 + 2], s4.z); atomicAdd(&ls[o4 + 3], s4.w);
    atomicAdd(&ls[128 + o4 + 0], ss4.x); atomicAdd(&ls[128 + o4 + 1], ss4.y);
    atomicAdd(&ls[128 + o4 + 2], ss4.z); atomicAdd(&ls[128 + o4 + 3], ss4.w);
    __syncthreads();
    if (t < 128) {
      atomicAdd(&stats[t], ls[t]);
      atomicAdd(&stats[128 + t], ls[128 + t]);
    }
    __syncthreads();  // drains vmem before the release below
    int* lastf = (int*)(smem + 1024);
    if (t == 0)
      *lastf = (__hip_atomic_fetch_add(lin_done, 1, __ATOMIC_ACQ_REL,
                                       __HIP_MEMORY_SCOPE_AGENT) == 511);
    __syncthreads();
    if (!*lastf) return;
    // BN finalize (sums complete: every contributor release-incremented)
    if (t < 128) {
      const float inv = 1.0f / (float)(B_ * N_);
      const float mean = stats[t] * inv;
      const float var = stats[128 + t] * inv - mean * mean;
      const float r = 1.0f / sqrtf(var + 1e-5f);
      const float sc = gamma[t] * r;
      stats[256 + t] = sc;
      stats[384 + t] = beta[t] - mean * sc;
    }
    __syncthreads();
    if (t == 0)
      __hip_atomic_store(stats_flag, 1, __ATOMIC_RELEASE,
                         __HIP_MEMORY_SCOPE_AGENT);
    return;
  }

  // ------------------------- kNN split block -------------------------
  {
    const int kid = id - (B_ + 512);
    const int qt = kid / (B_ * S);
    const int rem = kid % (B_ * S);
    const int b = rem / S;
    const int s = rem % S;
    const int KPS = N_ / S;
    const int KT = KPS / 128;
    float* Qs = (float*)smem;             // 16 KB
    float* Ks = (float*)(smem + 16384);   // 32 KB
    float* sd2 = (float*)(smem + 49152);  // 64*132*4 = 33 KB
    float* qq = (float*)(smem + 82944);
    float* ff = (float*)(smem + 83200);
    int* qid = (int*)(smem + 83712);      // kept live through merge phase
    int* mflag = (int*)(smem + 83968);
    const float* fb = features + (size_t)b * N_ * CIN_;

    if (t == 0) {
      while (__hip_atomic_load(&prog[b], __ATOMIC_ACQUIRE,
                               __HIP_MEMORY_SCOPE_AGENT) < qt + 1)
        __builtin_amdgcn_s_sleep(16);
    }
    __syncthreads();
    if (t < 64) qid[t] = fps_idx[b * M_ + qt * 64 + t];
    __syncthreads();
#pragma unroll
    for (int st = 0; st < 2; ++st) {
      const int iid = t + 512 * st;
      const int row = iid >> 4, c4 = iid & 15;
      const int pc = (c4 + (row >> 2)) & 15;
      const float4 v = *(const float4*)(fb + (size_t)qid[row] * CIN_ + c4 * 4);
      *(float4*)(&Qs[row * 64 + pc * 4]) = v;
    }
    __syncthreads();
    if (t < 64) {
      float sv = 0.f;
#pragma unroll
      for (int c4 = 0; c4 < 16; ++c4) {
        const int pc = (c4 + (t >> 2)) & 15;
        const float4 v = *(const float4*)(&Qs[t * 64 + pc * 4]);
        sv = fmaf(v.x, v.x, sv); sv = fmaf(v.y, v.y, sv);
        sv = fmaf(v.z, v.z, sv); sv = fmaf(v.w, v.w, sv);
      }
      qq[t] = sv;
    }

    u64 lst[16];
#pragma unroll
    for (int p = 0; p < 16; ++p) lst[p] = ~0ull;
    u64 worst = ~0ull;
    int wpos = 0;

    const int q0 = (t >> 5) * 4;
    const int k0 = (t & 31) * 4;
    const int sq = t >> 3;
    const int ssub = t & 7;

    for (int kt = 0; kt < KT; ++kt) {
      const int kb = s * KPS + kt * 128;
#pragma unroll
      for (int st = 0; st < 4; ++st) {
        const int iid = t + 512 * st;
        const int row = iid >> 4, c4 = iid & 15;
        const int pc = (c4 + (row >> 2)) & 15;
        const float4 v =
            *(const float4*)(fb + (size_t)(kb + row) * CIN_ + c4 * 4);
        *(float4*)(&Ks[row * 64 + pc * 4]) = v;
      }
      __syncthreads();
      if (t < 128) {
        float sv = 0.f;
#pragma unroll
        for (int c4 = 0; c4 < 16; ++c4) {
          const int pc = (c4 + (t >> 2)) & 15;
          const float4 v = *(const float4*)(&Ks[t * 64 + pc * 4]);
          sv = fmaf(v.x, v.x, sv); sv = fmaf(v.y, v.y, sv);
          sv = fmaf(v.z, v.z, sv); sv = fmaf(v.w, v.w, sv);
        }
        ff[t] = sv;
      }
      __syncthreads();
      float acc[4][4];
#pragma unroll
      for (int i = 0; i < 4; ++i)
#pragma unroll
        for (int j = 0; j < 4; ++j) acc[i][j] = 0.f;
#pragma unroll
      for (int c4 = 0; c4 < 16; ++c4) {
        float4 qv[4], kv[4];
#pragma unroll
        for (int i = 0; i < 4; ++i) {
          const int row = q0 + i;
          const int pc = (c4 + (row >> 2)) & 15;
          qv[i] = *(const float4*)(&Qs[row * 64 + pc * 4]);
        }
#pragma unroll
        for (int j = 0; j < 4; ++j) {
          const int row = k0 + j;
          const int pc = (c4 + (row >> 2)) & 15;
          kv[j] = *(const float4*)(&Ks[row * 64 + pc * 4]);
        }
#pragma unroll
        for (int i = 0; i < 4; ++i)
#pragma unroll
          for (int j = 0; j < 4; ++j) {
            acc[i][j] = fmaf(qv[i].x, kv[j].x, acc[i][j]);
            acc[i][j] = fmaf(qv[i].y, kv[j].y, acc[i][j]);
            acc[i][j] = fmaf(qv[i].z, kv[j].z, acc[i][j]);
            acc[i][j] = fmaf(qv[i].w, kv[j].w, acc[i][j]);
          }
      }
#pragma unroll
      for (int i = 0; i < 4; ++i) {
        const float qv = qq[q0 + i];
        float4 o;
        o.x = __fsub_rn(__fadd_rn(qv, ff[k0 + 0]), 2.f * acc[i][0]);
        o.y = __fsub_rn(__fadd_rn(qv, ff[k0 + 1]), 2.f * acc[i][1]);
        o.z = __fsub_rn(__fadd_rn(qv, ff[k0 + 2]), 2.f * acc[i][2]);
        o.w = __fsub_rn(__fadd_rn(qv, ff[k0 + 3]), 2.f * acc[i][3]);
        *(float4*)(&sd2[(q0 + i) * 132 + k0]) = o;
      }
      __syncthreads();
#pragma unroll
      for (int g = 0; g < 4; ++g) {
        const float4 v = *(const float4*)(&sd2[sq * 132 + ssub * 16 + g * 4]);
        const float dv[4] = {v.x, v.y, v.z, v.w};
#pragma unroll
        for (int jj = 0; jj < 4; ++jj) {
          const int key = kb + ssub * 16 + g * 4 + jj;
          const u64 pk = ((u64)mono32(dv[jj]) << 32) | (unsigned)key;
          if (pk < worst) {
#pragma unroll
            for (int p = 0; p < 16; ++p)
              if (p == wpos) lst[p] = pk;
            worst = lst[0]; wpos = 0;
#pragma unroll
            for (int p = 1; p < 16; ++p)
              if (lst[p] > worst) { worst = lst[p]; wpos = p; }
          }
        }
      }
      __syncthreads();
    }
    u64* cb = cand + ((size_t)(b * M_ + qt * 64 + sq) * S + s) * 16;
    for (int r = 0; r < K_; ++r) {
      u64 mn = lst[0];
#pragma unroll
      for (int p = 1; p < 16; ++p)
        if (lst[p] < mn) mn = lst[p];
      u64 m2 = mn;
#pragma unroll
      for (int off = 1; off < 8; off <<= 1) {
        const u64 o = __shfl_xor(m2, off, 64);
        if (o < m2) m2 = o;
      }
      if (mn == m2) {
        bool done = false;
#pragma unroll
        for (int p = 0; p < 16; ++p)
          if (!done && lst[p] == m2) { lst[p] = ~0ull; done = true; }
      }
      if (ssub == 0) cb[r] = m2;
    }
    __syncthreads();  // drain cand stores before release
    if (t == 0)
      *mflag = (__hip_atomic_fetch_add(&qt_done[b * 16 + qt], 1,
                                       __ATOMIC_ACQ_REL,
                                       __HIP_MEMORY_SCOPE_AGENT) == S - 1);
    __syncthreads();
    if (!*mflag) return;

    // ------------- merger: S sorted lists -> top16 -> gather/BN/max ---------
    u64* cl = (u64*)smem;                 // [64][S*16] up to 64 KB
    int* nbi = (int*)(smem + 65536);      // [64][16]
    float* scsh = (float*)(smem + 69632); // scale[128], shift[128]
    if (t == 0) {
      while (__hip_atomic_load(stats_flag, __ATOMIC_ACQUIRE,
                               __HIP_MEMORY_SCOPE_AGENT) == 0)
        __builtin_amdgcn_s_sleep(8);
    }
    __syncthreads();
    const int S16 = S * 16;
    const u64* cg = cand + (size_t)(b * M_ + qt * 64) * S16;
    for (int i = t; i < 64 * S16; i += 512) cl[i] = cg[i];
    if (t < 256) scsh[t] = stats[256 + t];
    __syncthreads();
    if (t < 64) {
      int ptr[8] = {0, 0, 0, 0, 0, 0, 0, 0};
      for (int r = 0; r < K_; ++r) {
        u64 mn = ~0ull;
        int ms = 0;
        for (int ss = 0; ss < S; ++ss) {
          if (ptr[ss] < 16) {
            const u64 v = cl[t * S16 + ss * 16 + ptr[ss]];
            if (v < mn) { mn = v; ms = ss; }
          }
        }
        nbi[t * 16 + r] = (int)(unsigned)(mn & 0xFFFFFFFFu);
        ptr[ms]++;
      }
    }
    __syncthreads();
    {
      const int q = t >> 3;          // 0..63
      const int c0 = (t & 7) * 16;   // channel base
      float sc[16], sh[16], mx[16];
#pragma unroll
      for (int i = 0; i < 16; ++i) {
        sc[i] = scsh[c0 + i];
        sh[i] = scsh[128 + c0 + i];
        mx[i] = -3.402823466e38f;
      }
#pragma unroll
      for (int k = 0; k < K_; ++k) {
        const int n = nbi[q * 16 + k];
        const uint4* hr =
            (const uint4*)(h + ((size_t)b * N_ + n) * COUT_ + c0);
        const uint4 h0 = hr[0];
        const uint4 h1 = hr[1];
        const unsigned hu[8] = {h0.x, h0.y, h0.z, h0.w, h1.x, h1.y, h1.z, h1.w};
#pragma unroll
        for (int i = 0; i < 8; ++i) {
          const float lo = __uint_as_float(hu[i] << 16);
          const float hi = __uint_as_float(hu[i] & 0xFFFF0000u);
          mx[2 * i] = fmaxf(mx[2 * i], fmaf(lo, sc[2 * i], sh[2 * i]));
          mx[2 * i + 1] = fmaxf(mx[2 * i + 1], fmaf(hi, sc[2 * i + 1], sh[2 * i + 1]));
        }
      }
      float* ob = out + (size_t)(b * M_ + qt * 64 + q) * COUT_ + c0;
#pragma unroll
      for (int i = 0; i < 4; ++i)
        *(float4*)(ob + 4 * i) =
            make_float4(mx[4 * i], mx[4 * i + 1], mx[4 * i + 2], mx[4 * i + 3]);
    }
    // positions + batch for these 64 queries
    if (t < 64) {
      const int q = t;
      const int Q = b * M_ + qt * 64 + q;
      const int idx = qid[q];
      const float* pr = pos + ((size_t)b * N_ + idx) * 3;
      out[A + Q * 3 + 0] = pr[0];
      out[A + Q * 3 + 1] = pr[1];
      out[A + Q * 3 + 2] = pr[2];
      float* base = out + A + P;
      if (batch_as_i64)
        ((long long*)base)[Q] = (long long)b;
      else
        base[Q] = (float)b;
    }
  }
}

extern "C" void kernel_launch(void* const* d_in, const int* in_sizes, int n_in,
                              void* d_out, int out_size, void* d_ws, size_t ws_size,
                              hipStream_t stream) {
  const float* features = (const float*)d_in[0];
  const float* positions = (const float*)d_in[1];
  const float* W = (const float*)d_in[3];
  const float* bias = (const float*)d_in[4];
  const float* gamma = (const float*)d_in[5];
  const float* beta = (const float*)d_in[6];
  float* out = (float*)d_out;
  unsigned char* ws = (unsigned char*)d_ws;

  int* fps_idx = (int*)ws;                            // 64 KB
  unsigned short* h = (unsigned short*)(ws + 65536);  // bf16, 16.8 MB
  const size_t hoff = 65536 + (size_t)B_ * N_ * COUT_ * 2;
  float* ctrl = (float*)(ws + hoff);                  // 4 KB control block
  u64* cand = (u64*)(ws + hoff + 4096);
  const size_t base = hoff + 4096;

  int S = 8;
  while (S > 1 && base + (size_t)B_ * M_ * S * 16 * 8 > ws_size) S >>= 1;

  const int rem = out_size - (B_ * M_ * COUT_) - (B_ * M_ * 3);
  const int batch_as_i64 = (rem >= 2 * B_ * M_) ? 1 : 0;

  hipMemsetAsync(ctrl, 0, 4096, stream);
  mega_kernel<<<B_ + 512 + 256 * S, 512, 0, stream>>>(
      positions, features, W, bias, gamma, beta, fps_idx, h, ctrl, cand, out,
      S, batch_as_i64);
}